// Round 1
// baseline (346.629 us; speedup 1.0000x reference)
//
#include <hip/hip_runtime.h>

// CRF loss forward: scores (512,128,48,48) f32, target (512,128) int, mask (512,128) int(bool)
// out: scalar f32 = (sum_b partition_b[END] - sum tg)/B

#define S_LEN 512
#define BATCH 128
#define T 48
#define TT (T * T) // 2304
#define START_TAG 46
#define END_TAG 47
#define NTHREADS 512
#define NGROUPS 8 // waves per block; each handles IPG i-rows
#define IPG 6     // 48 / 8

__global__ __launch_bounds__(NTHREADS) void crf_scan_kernel(
    const float* __restrict__ scores,
    const int* __restrict__ target,
    const int* __restrict__ mask,
    float* __restrict__ ws)
{
    __shared__ float tile[2][TT];
    __shared__ float p[T];
    __shared__ float red_m[NGROUPS][T];
    __shared__ float red_s[NGROUPS][T];
    __shared__ int lmask[S_LEN];
    __shared__ int ltgt[S_LEN];

    const int b = blockIdx.x;
    const int t = threadIdx.x;
    const int j = t & 63;        // output column (valid < 48)
    const int ic = t >> 6;       // i-group (0..7)
    const bool valid = (j < T);

    // preload mask/target columns for this batch (once, strided)
    lmask[t] = mask[(size_t)t * BATCH + b];
    ltgt[t] = target[(size_t)t * BATCH + b];

    // stage tile for s=0
    {
        const float4* src = (const float4*)(scores + (size_t)b * TT);
        float4 r0 = src[t];
        float4 r1;
        if (t < 64) r1 = src[512 + t];
        float4* dst = (float4*)tile[0];
        dst[t] = r0;
        if (t < 64) dst[512 + t] = r1;
    }
    __syncthreads();

    float tg_local = 0.0f;

    for (int s = 0; s < S_LEN; ++s) {
        const int buf = s & 1;

        // T14 async-stage: issue next tile's global loads BEFORE compute;
        // ds_write happens after barrier 1, so HBM latency hides under compute.
        float4 r0, r1;
        if (s + 1 < S_LEN) {
            const float4* src = (const float4*)(scores + ((size_t)(s + 1) * BATCH + b) * TT);
            r0 = src[t];
            if (t < 64) r1 = src[512 + t];
        }

        if (s == 0) {
            if (t < T) p[t] = tile[0][START_TAG * T + t];
            if (t == 0 && lmask[0]) tg_local += tile[0][ltgt[0]];
        } else {
            if (valid) {
                const int i0 = ic * IPG;
                float x[IPG];
                float m = -1e30f;
#pragma unroll
                for (int k = 0; k < IPG; ++k) {
                    x[k] = tile[buf][(i0 + k) * T + j] + p[i0 + k];
                    m = fmaxf(m, x[k]);
                }
                float sum = 0.0f;
#pragma unroll
                for (int k = 0; k < IPG; ++k) sum += __expf(x[k] - m);
                red_m[ic][j] = m;
                red_s[ic][j] = sum;
            }
            if (t == 0 && lmask[s]) tg_local += tile[buf][ltgt[s]];
        }
        __syncthreads(); // barrier 1: partials written, all tile[buf] reads done

        if (s > 0 && t < T) {
            float M = red_m[0][t];
#pragma unroll
            for (int g = 1; g < NGROUPS; ++g) M = fmaxf(M, red_m[g][t]);
            float Ssum = 0.0f;
#pragma unroll
            for (int g = 0; g < NGROUPS; ++g) Ssum += red_s[g][t] * __expf(red_m[g][t] - M);
            float cur = M + __logf(Ssum);
            if (lmask[s]) p[t] = cur;
        }

        // stage write of next tile into the other buffer (its readers finished
        // two barriers ago); loads issued at loop top have completed under compute
        if (s + 1 < S_LEN) {
            float4* dst = (float4*)tile[buf ^ 1];
            dst[t] = r0;
            if (t < 64) dst[512 + t] = r1;
        }
        __syncthreads(); // barrier 2: p + staged tile visible for next step
    }

    if (t == 0) ws[b] = p[END_TAG] - tg_local;
}

__global__ void crf_reduce_kernel(const float* __restrict__ ws, float* __restrict__ out)
{
    // single block; deterministic fixed-order sum of 128 per-batch partials
    __shared__ float sh[BATCH];
    int t = threadIdx.x;
    if (t < BATCH) sh[t] = ws[t];
    __syncthreads();
    if (t == 0) {
        float s = 0.0f;
        for (int k = 0; k < BATCH; ++k) s += sh[k];
        out[0] = s / (float)BATCH;
    }
}

extern "C" void kernel_launch(void* const* d_in, const int* in_sizes, int n_in,
                              void* d_out, int out_size, void* d_ws, size_t ws_size,
                              hipStream_t stream)
{
    const float* scores = (const float*)d_in[0];
    const int* target = (const int*)d_in[1];
    const int* mask = (const int*)d_in[2];
    float* ws = (float*)d_ws;
    float* out = (float*)d_out;

    crf_scan_kernel<<<BATCH, NTHREADS, 0, stream>>>(scores, target, mask, ws);
    crf_reduce_kernel<<<1, 128, 0, stream>>>(ws, out);
}